// Round 4
// baseline (98.357 us; speedup 1.0000x reference)
//
#include <hip/hip_runtime.h>
#include <hip/hip_bf16.h>
#include <stdint.h>

#define BB 16
#define NN 1024
#define MM 1024
#define DD 128
#define VERY_NEG (-1e30f)
#define LOG2E 1.44269504f

using bf16x8 = __attribute__((ext_vector_type(8))) short;
using f32x4  = __attribute__((ext_vector_type(4))) float;

__device__ inline unsigned short f2bf(float f) {
    union { float f; uint32_t u; } cv; cv.f = f;
    uint32_t u = cv.u;
    return (unsigned short)((u + 0x7FFFu + ((u >> 16) & 1u)) >> 16);
}
#define EXP2F(x) __builtin_amdgcn_exp2f(x)

// ---- prep: a = q.w_q (real scale); c1s = (c + mask_bias)*log2e;
//      qp = bf16(q*w_qm*log2e); mb = bf16(mem) ----
__global__ void prep_rows(const float* __restrict__ q, const float* __restrict__ mem,
                          const float* __restrict__ wq, const float* __restrict__ wm,
                          const float* __restrict__ wqm, const int* __restrict__ mmask,
                          float* __restrict__ a, float* __restrict__ c1s,
                          unsigned short* __restrict__ qp, unsigned short* __restrict__ mb)
{
    int wave = (blockIdx.x * 256 + threadIdx.x) >> 6;
    int lane = threadIdx.x & 63;
    bool is_q = wave < BB * NN;
    int row = is_q ? wave : wave - BB * NN;
    const float* src = (is_q ? q : mem) + (size_t)row * DD;
    const float* wd  = is_q ? wq : wm;
    float2 v  = *(const float2*)(src + lane * 2);
    float2 w2 = *(const float2*)(wd + lane * 2);
    float dot = v.x * w2.x + v.y * w2.y;
    #pragma unroll
    for (int o = 32; o; o >>= 1) dot += __shfl_xor(dot, o);
    if (lane == 0) {
        if (is_q) a[row] = dot;
        else {
            int mm = mmask[row];
            c1s[row] = (dot + (mm ? 0.f : VERY_NEG)) * LOG2E;
        }
    }
    float2 s2 = v;
    if (is_q) {
        float2 wv = *(const float2*)(wqm + lane * 2);
        s2.x *= wv.x * LOG2E; s2.y *= wv.y * LOG2E;
    }
    ushort2 o2; o2.x = f2bf(s2.x); o2.y = f2bf(s2.y);
    *(ushort2*)((is_q ? qp : mb) + (size_t)row * DD + lane * 2) = o2;
}

// ---- transpose memory into mt[b][d][m] (bf16) for the PV B-operand ----
__global__ void transpose_mem(const float* __restrict__ mem, unsigned short* __restrict__ mt)
{
    __shared__ unsigned short t[64][72];
    int bid = blockIdx.x;
    int dt = bid & 1, mtile = (bid >> 1) & 15, b = bid >> 5;
    int d0 = dt * 64, m0 = mtile * 64;
    int tid = threadIdx.x;
    int cc = tid & 63, rr = tid >> 6;
    #pragma unroll
    for (int r = 0; r < 64; r += 4) {
        float v = mem[((size_t)b * MM + m0 + r + rr) * DD + d0 + cc];
        t[cc][r + rr] = f2bf(v);
    }
    __syncthreads();
    #pragma unroll
    for (int r = 0; r < 64; r += 4) {
        mt[((size_t)b * DD + d0 + r + rr) * MM + m0 + cc] = t[r + rr][cc];
    }
}

// ---- flash main: 8 waves/block = 4 q-tiles (64 q) x 2 m-halves (512 m each).
//      Same-m waves walk chunks in lockstep -> shared L1 lines. 2-way LDS merge.
//      qm=0 rows: s forced to 0 (constant row) -> uniform softmax == reference
//      f32 absorption semantics. ----
__global__ __launch_bounds__(512) void flash_fwd(
    const unsigned short* __restrict__ qp, const unsigned short* __restrict__ mb,
    const unsigned short* __restrict__ mt,
    const float* __restrict__ a, const float* __restrict__ c1s,
    const int* __restrict__ qmask,
    float* __restrict__ out1, float* __restrict__ rowmax)
{
    __shared__ unsigned short pl[8][16][72];
    __shared__ float Obuf[4][16][130];
    __shared__ float mlb[8][16][2];

    int tid = threadIdx.x;
    int w = tid >> 6, lane = tid & 63;
    int qt = w & 3, mh = w >> 2;
    int g = lane >> 4, qi = lane & 15;
    int b = blockIdx.x >> 4, nt = blockIdx.x & 15;
    int n0q = nt * 64 + qt * 16;

    // Q' B-frags (log2e-prescaled): lane(g,qi) elem j = Q'[qi][kc*32+g*8+j]
    const unsigned short* qpb = qp + ((size_t)b * NN + n0q) * DD;
    bf16x8 qf[4];
    #pragma unroll
    for (int kc = 0; kc < 4; kc++)
        qf[kc] = *(const bf16x8*)(qpb + qi * DD + kc * 32 + g * 8);

    float a_q = a[b * NN + n0q + qi];
    int   qm  = qmask[b * NN + n0q + qi];

    float m_run = -INFINITY, l_run = 0.f;
    f32x4 o[8];
    #pragma unroll
    for (int d2 = 0; d2 < 8; d2++) o[d2] = (f32x4){0.f, 0.f, 0.f, 0.f};

    const unsigned short* mbB = mb + (size_t)b * MM * DD;
    const unsigned short* mtB = mt + (size_t)b * DD * MM;
    const float* c1B = c1s + b * MM;

    int mbase = mh * (MM / 2);
    for (int mc = 0; mc < MM / 2; mc += 64) {
        __builtin_amdgcn_s_barrier();   // keep same-m waves in lockstep for L1 sharing
        int m0 = mbase + mc;
        // S^T tiles (16m x 16q), 4 per 64-m chunk
        f32x4 st[4];
        #pragma unroll
        for (int t = 0; t < 4; t++) st[t] = (f32x4){0, 0, 0, 0};
        #pragma unroll
        for (int t = 0; t < 4; t++) {
            const unsigned short* arow = mbB + (size_t)(m0 + t * 16 + qi) * DD + g * 8;
            #pragma unroll
            for (int kc = 0; kc < 4; kc++) {
                bf16x8 af = *(const bf16x8*)(arow + kc * 32);
                st[t] = __builtin_amdgcn_mfma_f32_16x16x32_bf16(af, qf[kc], st[t], 0, 0, 0);
            }
        }
        // bias + mask; acc layout: lane(g,qi) reg i -> m = m0 + t*16 + g*4 + i, q = qi
        float sv[4][4];
        float cmax = -INFINITY;
        #pragma unroll
        for (int t = 0; t < 4; t++) {
            float4 c1v = *(const float4*)(c1B + m0 + t * 16 + g * 4);
            float cc4[4] = {c1v.x, c1v.y, c1v.z, c1v.w};
            #pragma unroll
            for (int i = 0; i < 4; i++) {
                float s = qm ? (st[t][i] + cc4[i]) : 0.f;   // qm=0: constant row -> uniform softmax
                sv[t][i] = s;
                cmax = fmaxf(cmax, s);
            }
        }
        cmax = fmaxf(cmax, __shfl_xor(cmax, 16));
        cmax = fmaxf(cmax, __shfl_xor(cmax, 32));
        float m_new = fmaxf(m_run, cmax);
        float alpha = EXP2F(m_run - m_new);
        float psum = 0.f;
        #pragma unroll
        for (int t = 0; t < 4; t++) {
            unsigned short pe[4];
            #pragma unroll
            for (int i = 0; i < 4; i++) {
                float p = EXP2F(sv[t][i] - m_new);
                psum += p;
                pe[i] = f2bf(p);
            }
            ushort4 pw; pw.x = pe[0]; pw.y = pe[1]; pw.z = pe[2]; pw.w = pe[3];
            *(ushort4*)(&pl[w][qi][t * 16 + g * 4]) = pw;   // P[q][mlocal]
        }
        psum += __shfl_xor(psum, 16);
        psum += __shfl_xor(psum, 32);
        l_run = l_run * alpha + psum;
        m_run = m_new;

        float aL[4];
        #pragma unroll
        for (int i = 0; i < 4; i++) aL[i] = __shfl(alpha, g * 4 + i);

        __builtin_amdgcn_sched_barrier(0);
        // PV: A-frag P[qi][kk*32+g*8+j] from LDS; B-frag Mem[m][d] from mt
        bf16x8 pa0 = *(const bf16x8*)(&pl[w][qi][g * 8]);
        bf16x8 pa1 = *(const bf16x8*)(&pl[w][qi][32 + g * 8]);
        #pragma unroll
        for (int d2 = 0; d2 < 8; d2++) {
            const unsigned short* vrow = mtB + (size_t)(d2 * 16 + qi) * MM + m0 + g * 8;
            bf16x8 vf0 = *(const bf16x8*)(vrow);
            bf16x8 vf1 = *(const bf16x8*)(vrow + 32);
            f32x4 oo = o[d2];
            #pragma unroll
            for (int i = 0; i < 4; i++) oo[i] *= aL[i];
            oo = __builtin_amdgcn_mfma_f32_16x16x32_bf16(pa0, vf0, oo, 0, 0, 0);
            o[d2] = __builtin_amdgcn_mfma_f32_16x16x32_bf16(pa1, vf1, oo, 0, 0, 0);
        }
    }

    // ---- 2-way merge across m-halves ----
    if (g == 0) { mlb[w][qi][0] = m_run; mlb[w][qi][1] = l_run; }
    __syncthreads();
    int pw = w ^ 4;
    float mo[4], mp[4];
    #pragma unroll
    for (int i = 0; i < 4; i++) {
        int r = g * 4 + i;
        mo[i] = __shfl(m_run, r);
        mp[i] = mlb[pw][r][0];
    }
    if (mh == 0) {
        #pragma unroll
        for (int i = 0; i < 4; i++) {
            float M = fmaxf(mo[i], mp[i]);
            float wsc = EXP2F(mo[i] - M);
            #pragma unroll
            for (int d2 = 0; d2 < 8; d2++)
                Obuf[qt][g * 4 + i][d2 * 16 + qi] = o[d2][i] * wsc;
        }
    }
    __syncthreads();
    if (mh == 1) {
        #pragma unroll
        for (int i = 0; i < 4; i++) {
            int r = g * 4 + i;
            float M = fmaxf(mo[i], mp[i]);
            float ws1 = EXP2F(mo[i] - M);
            float lo = __shfl(l_run, r);
            float lg = mlb[pw][r][1] * EXP2F(mp[i] - M) + lo * ws1;
            float invl = 1.f / lg;
            #pragma unroll
            for (int d2 = 0; d2 < 8; d2++) {
                float val = (Obuf[qt][r][d2 * 16 + qi] + o[d2][i] * ws1) * invl;
                out1[((size_t)b * NN + n0q + r) * DD + d2 * 16 + qi] = val;
            }
        }
        if (g == 0) {
            float M = fmaxf(m_run, mlb[pw][qi][0]);
            rowmax[b * NN + n0q + qi] = M * (1.f / LOG2E) + a_q + (qm ? 0.f : VERY_NEG);
        }
    }
}

// ---- m2q partials: block = (b, chunk of 128 n-rows) ----
__global__ __launch_bounds__(256) void m2q_partial(
    const float* __restrict__ rowmax, const float* __restrict__ query,
    float* __restrict__ partial, float* __restrict__ Zbuf)
{
    int bid = blockIdx.x;
    int b = bid >> 3, ch = bid & 7;
    int tid = threadIdx.x, lane = tid & 63, wv = tid >> 6;
    __shared__ float red[8];
    __shared__ float pe[128];
    __shared__ float acc1[128];

    float4 rv = *(const float4*)(rowmax + b * NN + tid * 4);
    float mx = fmaxf(fmaxf(rv.x, rv.y), fmaxf(rv.z, rv.w));
    #pragma unroll
    for (int o = 32; o; o >>= 1) mx = fmaxf(mx, __shfl_xor(mx, o));
    if (lane == 0) red[wv] = mx;
    __syncthreads();
    mx = fmaxf(fmaxf(red[0], red[1]), fmaxf(red[2], red[3]));
    float ls = __expf(rv.x - mx) + __expf(rv.y - mx) + __expf(rv.z - mx) + __expf(rv.w - mx);
    #pragma unroll
    for (int o = 32; o; o >>= 1) ls += __shfl_xor(ls, o);
    if (lane == 0) red[4 + wv] = ls;
    if (tid < 128) pe[tid] = __expf(rowmax[b * NN + ch * 128 + tid] - mx);
    __syncthreads();
    float Z = (red[4] + red[5]) + (red[6] + red[7]);

    int d = tid & 127, h = tid >> 7;
    const float* qb = query + ((size_t)b * NN + ch * 128 + h * 64) * DD + d;
    float acc = 0.f;
    #pragma unroll 8
    for (int n = 0; n < 64; n++) acc += pe[h * 64 + n] * qb[(size_t)n * DD];
    if (h) acc1[d] = acc;
    __syncthreads();
    if (!h) partial[(b * 8 + ch) * DD + d] = acc + acc1[d];
    if (tid == 0) Zbuf[b] = Z;
}

// ---- m2q final combine ----
__global__ void m2q_final(const float* __restrict__ partial, const float* __restrict__ Zbuf,
                          float* __restrict__ m2q)
{
    int b = blockIdx.x, d = threadIdx.x;
    float s = 0.f;
    #pragma unroll
    for (int ch = 0; ch < 8; ch++) s += partial[(b * 8 + ch) * DD + d];
    m2q[b * DD + d] = s / Zbuf[b];
}

// ---- broadcast m2q to out2[b][n][d] ----
__global__ void bcast_kernel(const float* __restrict__ m2q, float4* __restrict__ out2)
{
    int i = blockIdx.x * 256 + threadIdx.x;   // 524288 float4s
    int b = i >> 15;                          // N*D/4 = 32768
    int d4 = i & 31;                          // D/4 = 32
    out2[i] = ((const float4*)m2q)[(b << 5) + d4];
}

extern "C" void kernel_launch(void* const* d_in, const int* in_sizes, int n_in,
                              void* d_out, int out_size, void* d_ws, size_t ws_size,
                              hipStream_t stream)
{
    const float* query  = (const float*)d_in[0];
    const float* memory = (const float*)d_in[1];
    const float* w_q    = (const float*)d_in[2];
    const float* w_m    = (const float*)d_in[3];
    const float* w_qm   = (const float*)d_in[4];
    const int*   qmask  = (const int*)d_in[5];
    const int*   mmask  = (const int*)d_in[6];
    float* out1 = (float*)d_out;
    float* out2 = out1 + (size_t)BB * NN * DD;

    char* ws = (char*)d_ws;
    float* a       = (float*)ws;                 // B*N
    float* c1s     = a + BB * NN;                // B*M
    float* rowmax  = c1s + BB * MM;              // B*N
    float* m2q     = rowmax + BB * NN;           // B*D
    float* partial = m2q + BB * DD;              // B*8*D
    float* Zbuf    = partial + BB * 8 * DD;      // B
    unsigned short* qp = (unsigned short*)(ws + (1 << 20));
    unsigned short* mb = qp + (size_t)BB * NN * DD;
    unsigned short* mt = mb + (size_t)BB * MM * DD;

    prep_rows<<<dim3((BB * NN + BB * MM) / 4), 256, 0, stream>>>(query, memory, w_q, w_m, w_qm, mmask, a, c1s, qp, mb);
    transpose_mem<<<dim3(BB * (MM / 64) * (DD / 64)), 256, 0, stream>>>(memory, mt);
    flash_fwd<<<dim3(BB * 16), 512, 0, stream>>>(qp, mb, mt, a, c1s, qmask, out1, rowmax);
    m2q_partial<<<dim3(BB * 8), 256, 0, stream>>>(rowmax, query, partial, Zbuf);
    m2q_final<<<dim3(BB), 128, 0, stream>>>(partial, Zbuf, m2q);
    bcast_kernel<<<dim3(2048), 256, 0, stream>>>(m2q, (float4*)out2);
}

// Round 5
// 56.394 us; speedup vs baseline: 1.7441x; 1.7441x over previous
//
#include <hip/hip_runtime.h>
#include <hip/hip_bf16.h>
#include <stdint.h>

#define BB 16
#define NN 1024
#define MM 1024
#define DD 128
#define VERY_NEG (-1e30f)
#define LOG2E 1.44269504f
#define NCHUNK 16          // 64-m chunks

using bf16x8 = __attribute__((ext_vector_type(8))) short;
using f32x4  = __attribute__((ext_vector_type(4))) float;

__device__ inline unsigned short f2bf(float f) {
    union { float f; uint32_t u; } cv; cv.f = f;
    uint32_t u = cv.u;
    return (unsigned short)((u + 0x7FFFu + ((u >> 16) & 1u)) >> 16);
}
#define EXP2F(x) __builtin_amdgcn_exp2f(x)

typedef __attribute__((address_space(3))) unsigned int lds_u32;
typedef const __attribute__((address_space(1))) unsigned int glb_u32;
__device__ __forceinline__ void gl16(const void* g, void* l) {
    __builtin_amdgcn_global_load_lds((glb_u32*)g, (lds_u32*)l, 16, 0, 0);
}

// ---- prep: a = q.w_q (real scale); c1s = (c + mask_bias)*log2e;
//      qp = bf16(q*w_qm*log2e); mb = bf16(mem) ----
__global__ void prep_rows(const float* __restrict__ q, const float* __restrict__ mem,
                          const float* __restrict__ wq, const float* __restrict__ wm,
                          const float* __restrict__ wqm, const int* __restrict__ mmask,
                          float* __restrict__ a, float* __restrict__ c1s,
                          unsigned short* __restrict__ qp, unsigned short* __restrict__ mb)
{
    int wave = (blockIdx.x * 256 + threadIdx.x) >> 6;
    int lane = threadIdx.x & 63;
    bool is_q = wave < BB * NN;
    int row = is_q ? wave : wave - BB * NN;
    const float* src = (is_q ? q : mem) + (size_t)row * DD;
    const float* wd  = is_q ? wq : wm;
    float2 v  = *(const float2*)(src + lane * 2);
    float2 w2 = *(const float2*)(wd + lane * 2);
    float dot = v.x * w2.x + v.y * w2.y;
    #pragma unroll
    for (int o = 32; o; o >>= 1) dot += __shfl_xor(dot, o);
    if (lane == 0) {
        if (is_q) a[row] = dot;
        else {
            int mm = mmask[row];
            c1s[row] = (dot + (mm ? 0.f : VERY_NEG)) * LOG2E;
        }
    }
    float2 s2 = v;
    if (is_q) {
        float2 wv = *(const float2*)(wqm + lane * 2);
        s2.x *= wv.x * LOG2E; s2.y *= wv.y * LOG2E;
    }
    ushort2 o2; o2.x = f2bf(s2.x); o2.y = f2bf(s2.y);
    *(ushort2*)((is_q ? qp : mb) + (size_t)row * DD + lane * 2) = o2;
}

// ---- transpose memory into mt[b][d][m] (bf16) for the PV B-operand ----
__global__ void transpose_mem(const float* __restrict__ mem, unsigned short* __restrict__ mt)
{
    __shared__ unsigned short t[64][72];
    int bid = blockIdx.x;
    int dt = bid & 1, mtile = (bid >> 1) & 15, b = bid >> 5;
    int d0 = dt * 64, m0 = mtile * 64;
    int tid = threadIdx.x;
    int cc = tid & 63, rr = tid >> 6;
    #pragma unroll
    for (int r = 0; r < 64; r += 4) {
        float v = mem[((size_t)b * MM + m0 + r + rr) * DD + d0 + cc];
        t[cc][r + rr] = f2bf(v);
    }
    __syncthreads();
    #pragma unroll
    for (int r = 0; r < 64; r += 4) {
        mt[((size_t)b * DD + d0 + r + rr) * MM + m0 + cc] = t[r + rr][cc];
    }
}

// ---- flash main: 4 waves/block, each wave owns 16 q-rows, full m-walk.
//      K/V chunk tiles DMA'd to LDS in FRAGMENT ORDER (linear ds_read_b128),
//      double-buffered: stage(t+1) || compute(t), __syncthreads as pipeline barrier. ----
__global__ __launch_bounds__(256) void flash_fwd(
    const unsigned short* __restrict__ qp, const unsigned short* __restrict__ mb,
    const unsigned short* __restrict__ mt,
    const float* __restrict__ a, const float* __restrict__ c1s,
    const int* __restrict__ qmask,
    float* __restrict__ out1, float* __restrict__ rowmax)
{
    // fragment-order slots: K slot j (t=j>>2, kc=j&3), V slot j2 (d2=j2>>1, h=j2&1)
    // slot = 64 lanes x 16B = 1KB = 512 shorts
    __shared__ unsigned short Kb[2][8192];
    __shared__ unsigned short Vb[2][8192];
    __shared__ unsigned short pl[4][16][72];
    __shared__ float c1L[MM];

    int tid = threadIdx.x;
    int w = tid >> 6, lane = tid & 63;
    int g = lane >> 4, qi = lane & 15;
    int b = blockIdx.x >> 4, nt = blockIdx.x & 15;
    int n0q = nt * 64 + w * 16;

    const unsigned short* mbB = mb + (size_t)b * MM * DD;
    const unsigned short* mtB = mt + (size_t)b * DD * MM;

    // c1 biases -> LDS (once)
    {
        float4 cv = *(const float4*)(c1s + b * MM + tid * 4);
        *(float4*)&c1L[tid * 4] = cv;
    }

    // Q' B-frags (log2e-prescaled): lane(g,qi) elem j = Q'[qi][kc*32+g*8+j]
    const unsigned short* qpb = qp + ((size_t)b * NN + n0q) * DD;
    bf16x8 qf[4];
    #pragma unroll
    for (int kc = 0; kc < 4; kc++)
        qf[kc] = *(const bf16x8*)(qpb + qi * DD + kc * 32 + g * 8);

    float a_q = a[b * NN + n0q + qi];
    int   qm  = qmask[b * NN + n0q + qi];

    float m_run = -INFINITY, l_run = 0.f;
    f32x4 o[8];
    #pragma unroll
    for (int d2 = 0; d2 < 8; d2++) o[d2] = (f32x4){0.f, 0.f, 0.f, 0.f};

    // ---- staging: each wave issues its 8 of the 32 1KB slots ----
    auto stage = [&](int m0, unsigned short* Kc, unsigned short* Vc) {
        #pragma unroll
        for (int i = 0; i < 8; i++) {
            int j = w * 8 + i;
            if (j < 16) {
                const unsigned short* gsrc = mbB
                    + (size_t)(m0 + (j >> 2) * 16 + (lane & 15)) * DD
                    + (j & 3) * 32 + (lane >> 4) * 8;
                gl16(gsrc, Kc + j * 512);
            } else {
                int j2 = j - 16;
                const unsigned short* gsrc = mtB
                    + (size_t)((j2 >> 1) * 16 + (lane & 15)) * MM
                    + m0 + (j2 & 1) * 32 + (lane >> 4) * 8;
                gl16(gsrc, Vc + j2 * 512);
            }
        }
    };

    stage(0, Kb[0], Vb[0]);
    __syncthreads();   // vmcnt(0)+lgkmcnt(0) drain: chunk 0 + c1L in LDS

    int cur = 0;
    for (int ch = 0; ch < NCHUNK; ch++) {
        int m0 = ch * 64;
        if (ch + 1 < NCHUNK)
            stage(m0 + 64, Kb[cur ^ 1], Vb[cur ^ 1]);   // DMA overlaps compute below

        const unsigned short* Kc = Kb[cur];
        const unsigned short* Vc = Vb[cur];

        // S^T tiles (16m x 16q), 4 per 64-m chunk; K frags linear from LDS
        f32x4 st[4];
        #pragma unroll
        for (int t = 0; t < 4; t++) st[t] = (f32x4){0, 0, 0, 0};
        #pragma unroll
        for (int t = 0; t < 4; t++) {
            #pragma unroll
            for (int kc = 0; kc < 4; kc++) {
                bf16x8 af = *(const bf16x8*)(Kc + ((t * 4 + kc) * 64 + lane) * 8);
                st[t] = __builtin_amdgcn_mfma_f32_16x16x32_bf16(af, qf[kc], st[t], 0, 0, 0);
            }
        }
        // bias + mask; acc layout: lane(g,qi) reg i -> m = m0 + t*16 + g*4 + i, q = qi
        float sv[4][4];
        float cmax = -INFINITY;
        #pragma unroll
        for (int t = 0; t < 4; t++) {
            float4 c1v = *(const float4*)&c1L[m0 + t * 16 + g * 4];
            float cc4[4] = {c1v.x, c1v.y, c1v.z, c1v.w};
            #pragma unroll
            for (int i = 0; i < 4; i++) {
                float s = qm ? (st[t][i] + cc4[i]) : 0.f;   // qm=0: uniform softmax (ref semantics)
                sv[t][i] = s;
                cmax = fmaxf(cmax, s);
            }
        }
        cmax = fmaxf(cmax, __shfl_xor(cmax, 16));
        cmax = fmaxf(cmax, __shfl_xor(cmax, 32));
        float m_new = fmaxf(m_run, cmax);
        float alpha = EXP2F(m_run - m_new);
        float psum = 0.f;
        #pragma unroll
        for (int t = 0; t < 4; t++) {
            unsigned short pe[4];
            #pragma unroll
            for (int i = 0; i < 4; i++) {
                float p = EXP2F(sv[t][i] - m_new);
                psum += p;
                pe[i] = f2bf(p);
            }
            ushort4 pw2; pw2.x = pe[0]; pw2.y = pe[1]; pw2.z = pe[2]; pw2.w = pe[3];
            *(ushort4*)(&pl[w][qi][t * 16 + g * 4]) = pw2;   // P[q][mlocal]
        }
        psum += __shfl_xor(psum, 16);
        psum += __shfl_xor(psum, 32);
        l_run = l_run * alpha + psum;
        m_run = m_new;

        float aL[4];
        #pragma unroll
        for (int i = 0; i < 4; i++) aL[i] = __shfl(alpha, g * 4 + i);

        __builtin_amdgcn_sched_barrier(0);
        // PV: A-frag P[qi][kk*32+g*8+j] from pl; B-frag V linear from LDS
        bf16x8 pa0 = *(const bf16x8*)(&pl[w][qi][g * 8]);
        bf16x8 pa1 = *(const bf16x8*)(&pl[w][qi][32 + g * 8]);
        #pragma unroll
        for (int d2 = 0; d2 < 8; d2++) {
            bf16x8 vf0 = *(const bf16x8*)(Vc + ((d2 * 2 + 0) * 64 + lane) * 8);
            bf16x8 vf1 = *(const bf16x8*)(Vc + ((d2 * 2 + 1) * 64 + lane) * 8);
            f32x4 oo = o[d2];
            #pragma unroll
            for (int i = 0; i < 4; i++) oo[i] *= aL[i];
            oo = __builtin_amdgcn_mfma_f32_16x16x32_bf16(pa0, vf0, oo, 0, 0, 0);
            o[d2] = __builtin_amdgcn_mfma_f32_16x16x32_bf16(pa1, vf1, oo, 0, 0, 0);
        }

        __syncthreads();   // drains vmcnt(0): chunk t+1 landed; all waves done with buf[cur]
        cur ^= 1;
    }

    // ---- epilogue: normalize + store ----
    float inv[4];
    #pragma unroll
    for (int i = 0; i < 4; i++) inv[i] = 1.f / __shfl(l_run, g * 4 + i);
    #pragma unroll
    for (int d2 = 0; d2 < 8; d2++) {
        #pragma unroll
        for (int i = 0; i < 4; i++)
            out1[((size_t)b * NN + n0q + g * 4 + i) * DD + d2 * 16 + qi] = o[d2][i] * inv[i];
    }
    if (lane < 16)
        rowmax[b * NN + n0q + qi] = m_run * (1.f / LOG2E) + a_q + (qm ? 0.f : VERY_NEG);
}

// ---- m2q partials: block = (b, chunk of 128 n-rows) ----
__global__ __launch_bounds__(256) void m2q_partial(
    const float* __restrict__ rowmax, const float* __restrict__ query,
    float* __restrict__ partial, float* __restrict__ Zbuf)
{
    int bid = blockIdx.x;
    int b = bid >> 3, ch = bid & 7;
    int tid = threadIdx.x, lane = tid & 63, wv = tid >> 6;
    __shared__ float red[8];
    __shared__ float pe[128];
    __shared__ float acc1[128];

    float4 rv = *(const float4*)(rowmax + b * NN + tid * 4);
    float mx = fmaxf(fmaxf(rv.x, rv.y), fmaxf(rv.z, rv.w));
    #pragma unroll
    for (int o = 32; o; o >>= 1) mx = fmaxf(mx, __shfl_xor(mx, o));
    if (lane == 0) red[wv] = mx;
    __syncthreads();
    mx = fmaxf(fmaxf(red[0], red[1]), fmaxf(red[2], red[3]));
    float ls = __expf(rv.x - mx) + __expf(rv.y - mx) + __expf(rv.z - mx) + __expf(rv.w - mx);
    #pragma unroll
    for (int o = 32; o; o >>= 1) ls += __shfl_xor(ls, o);
    if (lane == 0) red[4 + wv] = ls;
    if (tid < 128) pe[tid] = __expf(rowmax[b * NN + ch * 128 + tid] - mx);
    __syncthreads();
    float Z = (red[4] + red[5]) + (red[6] + red[7]);

    int d = tid & 127, h = tid >> 7;
    const float* qb = query + ((size_t)b * NN + ch * 128 + h * 64) * DD + d;
    float acc = 0.f;
    #pragma unroll 8
    for (int n = 0; n < 64; n++) acc += pe[h * 64 + n] * qb[(size_t)n * DD];
    if (h) acc1[d] = acc;
    __syncthreads();
    if (!h) partial[(b * 8 + ch) * DD + d] = acc + acc1[d];
    if (tid == 0) Zbuf[b] = Z;
}

// ---- bcast (fused final combine): out2[b][n][d] = (sum_ch partial)/Z ----
__global__ __launch_bounds__(256) void bcast_kernel(
    const float* __restrict__ partial, const float* __restrict__ Zbuf,
    float4* __restrict__ out2)
{
    __shared__ float m2qL[128];
    int i = blockIdx.x * 256 + threadIdx.x;   // 524288 float4s; 128 blocks per b
    int b = i >> 15;
    int tid = threadIdx.x;
    if (tid < 128) {
        float s = 0.f;
        #pragma unroll
        for (int ch = 0; ch < 8; ch++) s += partial[(b * 8 + ch) * DD + tid];
        m2qL[tid] = s / Zbuf[b];
    }
    __syncthreads();
    out2[i] = ((const float4*)m2qL)[i & 31];
}

extern "C" void kernel_launch(void* const* d_in, const int* in_sizes, int n_in,
                              void* d_out, int out_size, void* d_ws, size_t ws_size,
                              hipStream_t stream)
{
    const float* query  = (const float*)d_in[0];
    const float* memory = (const float*)d_in[1];
    const float* w_q    = (const float*)d_in[2];
    const float* w_m    = (const float*)d_in[3];
    const float* w_qm   = (const float*)d_in[4];
    const int*   qmask  = (const int*)d_in[5];
    const int*   mmask  = (const int*)d_in[6];
    float* out1 = (float*)d_out;
    float* out2 = out1 + (size_t)BB * NN * DD;

    char* ws = (char*)d_ws;
    float* a       = (float*)ws;                 // B*N
    float* c1s     = a + BB * NN;                // B*M
    float* rowmax  = c1s + BB * MM;              // B*N
    float* partial = rowmax + BB * NN;           // B*8*D
    float* Zbuf    = partial + BB * 8 * DD;      // B
    unsigned short* qp = (unsigned short*)(ws + (1 << 20));
    unsigned short* mb = qp + (size_t)BB * NN * DD;
    unsigned short* mt = mb + (size_t)BB * MM * DD;

    prep_rows<<<dim3((BB * NN + BB * MM) / 4), 256, 0, stream>>>(query, memory, w_q, w_m, w_qm, mmask, a, c1s, qp, mb);
    transpose_mem<<<dim3(BB * (MM / 64) * (DD / 64)), 256, 0, stream>>>(memory, mt);
    flash_fwd<<<dim3(BB * 16), 256, 0, stream>>>(qp, mb, mt, a, c1s, qmask, out1, rowmax);
    m2q_partial<<<dim3(BB * 8), 256, 0, stream>>>(rowmax, query, partial, Zbuf);
    bcast_kernel<<<dim3(2048), 256, 0, stream>>>(partial, Zbuf, (float4*)out2);
}

// Round 6
// 55.475 us; speedup vs baseline: 1.7730x; 1.0166x over previous
//
#include <hip/hip_runtime.h>
#include <hip/hip_bf16.h>
#include <stdint.h>

#define BB 16
#define NN 1024
#define MM 1024
#define DD 128
#define VERY_NEG (-1e30f)
#define LOG2E 1.44269504f
#define HALF_M 512
#define NCH 8              // 64-m chunks per half

using bf16x8 = __attribute__((ext_vector_type(8))) short;
using f32x4  = __attribute__((ext_vector_type(4))) float;

__device__ inline unsigned short f2bf(float f) {
    union { float f; uint32_t u; } cv; cv.f = f;
    uint32_t u = cv.u;
    return (unsigned short)((u + 0x7FFFu + ((u >> 16) & 1u)) >> 16);
}
#define EXP2F(x) __builtin_amdgcn_exp2f(x)

typedef __attribute__((address_space(3))) unsigned int lds_u32;
typedef const __attribute__((address_space(1))) unsigned int glb_u32;
__device__ __forceinline__ void gl16(const void* g, void* l) {
    __builtin_amdgcn_global_load_lds((glb_u32*)g, (lds_u32*)l, 16, 0, 0);
}

// ---- prep: a = q.w_q (real scale); c1s = (c + mask_bias)*log2e;
//      qp = bf16(q*w_qm*log2e); mb = bf16(mem) ----
__global__ void prep_rows(const float* __restrict__ q, const float* __restrict__ mem,
                          const float* __restrict__ wq, const float* __restrict__ wm,
                          const float* __restrict__ wqm, const int* __restrict__ mmask,
                          float* __restrict__ a, float* __restrict__ c1s,
                          unsigned short* __restrict__ qp, unsigned short* __restrict__ mb)
{
    int wave = (blockIdx.x * 256 + threadIdx.x) >> 6;
    int lane = threadIdx.x & 63;
    bool is_q = wave < BB * NN;
    int row = is_q ? wave : wave - BB * NN;
    const float* src = (is_q ? q : mem) + (size_t)row * DD;
    const float* wd  = is_q ? wq : wm;
    float2 v  = *(const float2*)(src + lane * 2);
    float2 w2 = *(const float2*)(wd + lane * 2);
    float dot = v.x * w2.x + v.y * w2.y;
    #pragma unroll
    for (int o = 32; o; o >>= 1) dot += __shfl_xor(dot, o);
    if (lane == 0) {
        if (is_q) a[row] = dot;
        else {
            int mm = mmask[row];
            c1s[row] = (dot + (mm ? 0.f : VERY_NEG)) * LOG2E;
        }
    }
    float2 s2 = v;
    if (is_q) {
        float2 wv = *(const float2*)(wqm + lane * 2);
        s2.x *= wv.x * LOG2E; s2.y *= wv.y * LOG2E;
    }
    ushort2 o2; o2.x = f2bf(s2.x); o2.y = f2bf(s2.y);
    *(ushort2*)((is_q ? qp : mb) + (size_t)row * DD + lane * 2) = o2;
}

// ---- transpose memory into mt[b][d][m] (bf16) for the PV B-operand ----
__global__ void transpose_mem(const float* __restrict__ mem, unsigned short* __restrict__ mt)
{
    __shared__ unsigned short t[64][72];
    int bid = blockIdx.x;
    int dt = bid & 1, mtile = (bid >> 1) & 15, b = bid >> 5;
    int d0 = dt * 64, m0 = mtile * 64;
    int tid = threadIdx.x;
    int cc = tid & 63, rr = tid >> 6;
    #pragma unroll
    for (int r = 0; r < 64; r += 4) {
        float v = mem[((size_t)b * MM + m0 + r + rr) * DD + d0 + cc];
        t[cc][r + rr] = f2bf(v);
    }
    __syncthreads();
    #pragma unroll
    for (int r = 0; r < 64; r += 4) {
        mt[((size_t)b * DD + d0 + r + rr) * MM + m0 + cc] = t[r + rr][cc];
    }
}

// ---- flash main: 8 waves/block = 4 q-tiles x 2 m-halves. Each half-group runs its
//      own double-buffered global_load_lds pipeline over 512 m (8 chunks of 64);
//      in-block 2-way LDS merge at the end (R4-verified math). ----
__global__ __launch_bounds__(512) void flash_fwd(
    const unsigned short* __restrict__ qp, const unsigned short* __restrict__ mb,
    const unsigned short* __restrict__ mt,
    const float* __restrict__ a, const float* __restrict__ c1s,
    const int* __restrict__ qmask,
    float* __restrict__ out1, float* __restrict__ rowmax)
{
    // manual smem partition (152KB): K/V staging 128KB | pl 18KB | c1 4KB | mlb 1KB
    // Obuf (merge scratch, 33KB) aliases the K buffers after the chunk loop.
    __shared__ __align__(16) char smem[155648];
    unsigned short* KbBase = (unsigned short*)smem;                  // [h][buf] 16KB slots
    unsigned short* VbBase = (unsigned short*)(smem + 65536);
    unsigned short (*pl)[16][72] = (unsigned short(*)[16][72])(smem + 131072);
    float* c1L = (float*)(smem + 149504);
    float (*mlb)[16][2] = (float(*)[16][2])(smem + 153600);
    float (*Obuf)[16][130] = (float(*)[16][130])smem;                // alias, post-loop

    int tid = threadIdx.x;
    int w = tid >> 6, lane = tid & 63;
    int qt = w & 3, mh = w >> 2;
    int g = lane >> 4, qi = lane & 15;
    int b = blockIdx.x >> 4, nt = blockIdx.x & 15;
    int n0q = nt * 64 + qt * 16;

    const unsigned short* mbB = mb + (size_t)b * MM * DD;
    const unsigned short* mtB = mt + (size_t)b * DD * MM;

    // c1 biases -> LDS (once)
    {
        float2 cv = *(const float2*)(c1s + b * MM + tid * 2);
        *(float2*)&c1L[tid * 2] = cv;
    }

    // Q' B-frags (log2e-prescaled): lane(g,qi) elem j = Q'[qi][kc*32+g*8+j]
    const unsigned short* qpb = qp + ((size_t)b * NN + n0q) * DD;
    bf16x8 qf[4];
    #pragma unroll
    for (int kc = 0; kc < 4; kc++)
        qf[kc] = *(const bf16x8*)(qpb + qi * DD + kc * 32 + g * 8);

    float a_q = a[b * NN + n0q + qi];
    int   qm  = qmask[b * NN + n0q + qi];

    float m_run = -INFINITY, l_run = 0.f;
    f32x4 o[8];
    #pragma unroll
    for (int d2 = 0; d2 < 8; d2++) o[d2] = (f32x4){0.f, 0.f, 0.f, 0.f};

    // ---- staging: the 4 waves of a half each issue 8 of its 32 1KB slots ----
    auto stage = [&](int m0, unsigned short* Kc, unsigned short* Vc) {
        #pragma unroll
        for (int i = 0; i < 8; i++) {
            int j = qt * 8 + i;
            if (j < 16) {
                const unsigned short* gsrc = mbB
                    + (size_t)(m0 + (j >> 2) * 16 + (lane & 15)) * DD
                    + (j & 3) * 32 + (lane >> 4) * 8;
                gl16(gsrc, Kc + j * 512);
            } else {
                int j2 = j - 16;
                const unsigned short* gsrc = mtB
                    + (size_t)((j2 >> 1) * 16 + (lane & 15)) * MM
                    + m0 + (j2 & 1) * 32 + (lane >> 4) * 8;
                gl16(gsrc, Vc + j2 * 512);
            }
        }
    };
    auto Kbuf = [&](int bufi) { return KbBase + (mh * 2 + bufi) * 8192; };
    auto Vbuf = [&](int bufi) { return VbBase + (mh * 2 + bufi) * 8192; };

    stage(mh * HALF_M, Kbuf(0), Vbuf(0));
    __syncthreads();   // vmcnt(0)+lgkmcnt(0) drain: chunk 0 + c1L in LDS

    int cur = 0;
    for (int ch = 0; ch < NCH; ch++) {
        int m0 = mh * HALF_M + ch * 64;
        if (ch + 1 < NCH)
            stage(m0 + 64, Kbuf(cur ^ 1), Vbuf(cur ^ 1));   // DMA overlaps compute below

        const unsigned short* Kc = Kbuf(cur);
        const unsigned short* Vc = Vbuf(cur);

        // S^T tiles (16m x 16q), 4 per 64-m chunk; K frags linear from LDS
        f32x4 st[4];
        #pragma unroll
        for (int t = 0; t < 4; t++) st[t] = (f32x4){0, 0, 0, 0};
        #pragma unroll
        for (int t = 0; t < 4; t++) {
            #pragma unroll
            for (int kc = 0; kc < 4; kc++) {
                bf16x8 af = *(const bf16x8*)(Kc + ((t * 4 + kc) * 64 + lane) * 8);
                st[t] = __builtin_amdgcn_mfma_f32_16x16x32_bf16(af, qf[kc], st[t], 0, 0, 0);
            }
        }
        // bias + mask; acc layout: lane(g,qi) reg i -> m = m0 + t*16 + g*4 + i, q = qi
        float sv[4][4];
        float cmax = -INFINITY;
        #pragma unroll
        for (int t = 0; t < 4; t++) {
            float4 c1v = *(const float4*)&c1L[m0 + t * 16 + g * 4];
            float cc4[4] = {c1v.x, c1v.y, c1v.z, c1v.w};
            #pragma unroll
            for (int i = 0; i < 4; i++) {
                float s = qm ? (st[t][i] + cc4[i]) : 0.f;   // qm=0: uniform softmax (ref semantics)
                sv[t][i] = s;
                cmax = fmaxf(cmax, s);
            }
        }
        cmax = fmaxf(cmax, __shfl_xor(cmax, 16));
        cmax = fmaxf(cmax, __shfl_xor(cmax, 32));
        float m_new = fmaxf(m_run, cmax);
        float alpha = EXP2F(m_run - m_new);
        float psum = 0.f;
        #pragma unroll
        for (int t = 0; t < 4; t++) {
            unsigned short pe[4];
            #pragma unroll
            for (int i = 0; i < 4; i++) {
                float p = EXP2F(sv[t][i] - m_new);
                psum += p;
                pe[i] = f2bf(p);
            }
            ushort4 pw2; pw2.x = pe[0]; pw2.y = pe[1]; pw2.z = pe[2]; pw2.w = pe[3];
            *(ushort4*)(&pl[w][qi][t * 16 + g * 4]) = pw2;   // P[q][mlocal]
        }
        psum += __shfl_xor(psum, 16);
        psum += __shfl_xor(psum, 32);
        l_run = l_run * alpha + psum;
        m_run = m_new;

        float aL[4];
        #pragma unroll
        for (int i = 0; i < 4; i++) aL[i] = __shfl(alpha, g * 4 + i);

        __builtin_amdgcn_sched_barrier(0);
        // PV: A-frag P[qi][kk*32+g*8+j] from pl; B-frag V linear from LDS
        bf16x8 pa0 = *(const bf16x8*)(&pl[w][qi][g * 8]);
        bf16x8 pa1 = *(const bf16x8*)(&pl[w][qi][32 + g * 8]);
        #pragma unroll
        for (int d2 = 0; d2 < 8; d2++) {
            bf16x8 vf0 = *(const bf16x8*)(Vc + ((d2 * 2 + 0) * 64 + lane) * 8);
            bf16x8 vf1 = *(const bf16x8*)(Vc + ((d2 * 2 + 1) * 64 + lane) * 8);
            f32x4 oo = o[d2];
            #pragma unroll
            for (int i = 0; i < 4; i++) oo[i] *= aL[i];
            oo = __builtin_amdgcn_mfma_f32_16x16x32_bf16(pa0, vf0, oo, 0, 0, 0);
            o[d2] = __builtin_amdgcn_mfma_f32_16x16x32_bf16(pa1, vf1, oo, 0, 0, 0);
        }

        __syncthreads();   // drains vmcnt(0): chunk t+1 landed; all waves done with buf[cur]
        cur ^= 1;
    }

    // ---- 2-way merge across m-halves (R4-verified) ----
    if (g == 0) { mlb[w][qi][0] = m_run; mlb[w][qi][1] = l_run; }
    __syncthreads();
    int pw = w ^ 4;
    float mo[4], mp[4];
    #pragma unroll
    for (int i = 0; i < 4; i++) {
        int r = g * 4 + i;
        mo[i] = __shfl(m_run, r);
        mp[i] = mlb[pw][r][0];
    }
    if (mh == 0) {
        #pragma unroll
        for (int i = 0; i < 4; i++) {
            float M = fmaxf(mo[i], mp[i]);
            float wsc = EXP2F(mo[i] - M);
            #pragma unroll
            for (int d2 = 0; d2 < 8; d2++)
                Obuf[qt][g * 4 + i][d2 * 16 + qi] = o[d2][i] * wsc;
        }
    }
    __syncthreads();
    if (mh == 1) {
        #pragma unroll
        for (int i = 0; i < 4; i++) {
            int r = g * 4 + i;
            float M = fmaxf(mo[i], mp[i]);
            float ws1 = EXP2F(mo[i] - M);
            float lo = __shfl(l_run, r);
            float lg = mlb[pw][r][1] * EXP2F(mp[i] - M) + lo * ws1;
            float invl = 1.f / lg;
            #pragma unroll
            for (int d2 = 0; d2 < 8; d2++) {
                float val = (Obuf[qt][r][d2 * 16 + qi] + o[d2][i] * ws1) * invl;
                out1[((size_t)b * NN + n0q + r) * DD + d2 * 16 + qi] = val;
            }
        }
        if (g == 0) {
            float M = fmaxf(m_run, mlb[pw][qi][0]);
            rowmax[b * NN + n0q + qi] = M * (1.f / LOG2E) + a_q + (qm ? 0.f : VERY_NEG);
        }
    }
}

// ---- m2q partials: block = (b, chunk of 128 n-rows) ----
__global__ __launch_bounds__(256) void m2q_partial(
    const float* __restrict__ rowmax, const float* __restrict__ query,
    float* __restrict__ partial, float* __restrict__ Zbuf)
{
    int bid = blockIdx.x;
    int b = bid >> 3, ch = bid & 7;
    int tid = threadIdx.x, lane = tid & 63, wv = tid >> 6;
    __shared__ float red[8];
    __shared__ float pe[128];
    __shared__ float acc1[128];

    float4 rv = *(const float4*)(rowmax + b * NN + tid * 4);
    float mx = fmaxf(fmaxf(rv.x, rv.y), fmaxf(rv.z, rv.w));
    #pragma unroll
    for (int o = 32; o; o >>= 1) mx = fmaxf(mx, __shfl_xor(mx, o));
    if (lane == 0) red[wv] = mx;
    __syncthreads();
    mx = fmaxf(fmaxf(red[0], red[1]), fmaxf(red[2], red[3]));
    float ls = __expf(rv.x - mx) + __expf(rv.y - mx) + __expf(rv.z - mx) + __expf(rv.w - mx);
    #pragma unroll
    for (int o = 32; o; o >>= 1) ls += __shfl_xor(ls, o);
    if (lane == 0) red[4 + wv] = ls;
    if (tid < 128) pe[tid] = __expf(rowmax[b * NN + ch * 128 + tid] - mx);
    __syncthreads();
    float Z = (red[4] + red[5]) + (red[6] + red[7]);

    int d = tid & 127, h = tid >> 7;
    const float* qb = query + ((size_t)b * NN + ch * 128 + h * 64) * DD + d;
    float acc = 0.f;
    #pragma unroll 8
    for (int n = 0; n < 64; n++) acc += pe[h * 64 + n] * qb[(size_t)n * DD];
    if (h) acc1[d] = acc;
    __syncthreads();
    if (!h) partial[(b * 8 + ch) * DD + d] = acc + acc1[d];
    if (tid == 0) Zbuf[b] = Z;
}

// ---- bcast (fused final combine): out2[b][n][d] = (sum_ch partial)/Z ----
__global__ __launch_bounds__(256) void bcast_kernel(
    const float* __restrict__ partial, const float* __restrict__ Zbuf,
    float4* __restrict__ out2)
{
    __shared__ float m2qL[128];
    int i = blockIdx.x * 256 + threadIdx.x;   // 524288 float4s; 128 blocks per b
    int b = i >> 15;
    int tid = threadIdx.x;
    if (tid < 128) {
        float s = 0.f;
        #pragma unroll
        for (int ch = 0; ch < 8; ch++) s += partial[(b * 8 + ch) * DD + tid];
        m2qL[tid] = s / Zbuf[b];
    }
    __syncthreads();
    out2[i] = ((const float4*)m2qL)[i & 31];
}

extern "C" void kernel_launch(void* const* d_in, const int* in_sizes, int n_in,
                              void* d_out, int out_size, void* d_ws, size_t ws_size,
                              hipStream_t stream)
{
    const float* query  = (const float*)d_in[0];
    const float* memory = (const float*)d_in[1];
    const float* w_q    = (const float*)d_in[2];
    const float* w_m    = (const float*)d_in[3];
    const float* w_qm   = (const float*)d_in[4];
    const int*   qmask  = (const int*)d_in[5];
    const int*   mmask  = (const int*)d_in[6];
    float* out1 = (float*)d_out;
    float* out2 = out1 + (size_t)BB * NN * DD;

    char* ws = (char*)d_ws;
    float* a       = (float*)ws;                 // B*N
    float* c1s     = a + BB * NN;                // B*M
    float* rowmax  = c1s + BB * MM;              // B*N
    float* partial = rowmax + BB * NN;           // B*8*D
    float* Zbuf    = partial + BB * 8 * DD;      // B
    unsigned short* qp = (unsigned short*)(ws + (1 << 20));
    unsigned short* mb = qp + (size_t)BB * NN * DD;
    unsigned short* mt = mb + (size_t)BB * MM * DD;

    prep_rows<<<dim3((BB * NN + BB * MM) / 4), 256, 0, stream>>>(query, memory, w_q, w_m, w_qm, mmask, a, c1s, qp, mb);
    transpose_mem<<<dim3(BB * (MM / 64) * (DD / 64)), 256, 0, stream>>>(memory, mt);
    flash_fwd<<<dim3(BB * 16), 512, 0, stream>>>(qp, mb, mt, a, c1s, qmask, out1, rowmax);
    m2q_partial<<<dim3(BB * 8), 256, 0, stream>>>(rowmax, query, partial, Zbuf);
    bcast_kernel<<<dim3(2048), 256, 0, stream>>>(partial, Zbuf, (float4*)out2);
}